// Round 7
// baseline (110.554 us; speedup 1.0000x reference)
//
#include <hip/hip_runtime.h>

typedef __attribute__((ext_vector_type(8))) short short8;
typedef __attribute__((ext_vector_type(8))) unsigned short ushort8;
typedef __attribute__((ext_vector_type(4))) float floatx4;
typedef __attribute__((ext_vector_type(4))) unsigned int uintx4;

constexpr int B = 8, Cin = 64, Hh = 128, Ww = 128, Cout = 64, Kt = 9, Ho = 128, Wo = 128;

__device__ __forceinline__ unsigned short f2bf(float f) {
    unsigned int u = __float_as_uint(f);
    unsigned int r = (u + 0x7fffu + ((u >> 16) & 1u)) >> 16;   // RTNE
    return (unsigned short)r;
}
__device__ __forceinline__ unsigned int cvtpk(float lo, float hi) {
    unsigned int r;
    asm("v_cvt_pk_bf16_f32 %0, %1, %2" : "=v"(r) : "v"(lo), "v"(hi));
    return r;
}
__device__ __forceinline__ float dot2bf(unsigned int a, unsigned int b, float c) {
    float d;
    asm("v_dot2_f32_bf16 %0, %1, %2, %3" : "=v"(d) : "v"(a), "v"(b), "v"(c));
    return d;
}

// ---------------- prep: weight -> per-lane A-fragment order
// wA2[(((k*2+h)*4+g)*64 + l)*8 + j] = bf16(w[cout][c][k])
//   cout = g*16 + (l&15), c = h*32 + (l>>4)*8 + j
__global__ void prep_w(const float* __restrict__ w, unsigned short* __restrict__ wA2) {
    int i = blockIdx.x * 256 + threadIdx.x;           // over Cout*Cin*Kt = 36864
    if (i >= Cout * Cin * Kt) return;
    int o = i / (Cin * Kt);
    int r = i % (Cin * Kt);
    int c = r / Kt;
    int k = r % Kt;
    const int h = c >> 5, sub = (c >> 3) & 3, j = c & 7;
    const int l = sub * 16 + (o & 15);
    const int g = o >> 4;
    wA2[(size_t)(((k * 2 + h) * 4 + g) * 64 + l) * 8 + j] = f2bf(w[i]);
}

// ---------------- prep: NCHW fp32 -> NHWC bf16
__global__ __launch_bounds__(256) void to_nhwc(const float* __restrict__ in,
                                               unsigned short* __restrict__ xn) {
    __shared__ float s[64 * 65];
    const int t = threadIdx.x;
    const int blk = blockIdx.x;               // b*256 + y*2 + xh
    const int b = blk >> 8;
    const int y = (blk & 255) >> 1;
    const int x0 = (blk & 1) * 64;
    const float* src = in + ((size_t)(b * 64) * 128 + y) * 128 + x0;  // in[b][0][y][x0]
    #pragma unroll
    for (int i = 0; i < 16; ++i) {
        int c = i * 4 + (t >> 6);
        s[c * 65 + (t & 63)] = src[(size_t)c * 16384 + (t & 63)];
    }
    __syncthreads();
    const int x = t >> 2, c0 = (t & 3) * 16;
    ushort8 o0, o1;
    #pragma unroll
    for (int j = 0; j < 8; ++j) {
        o0[j] = f2bf(s[(c0 + j) * 65 + x]);
        o1[j] = f2bf(s[(c0 + 8 + j) * 65 + x]);
    }
    unsigned short* dst = xn + (((size_t)(b * 128 + y) * 128 + x0 + x) * 64 + c0);
    *(ushort8*)dst = o0;
    *(ushort8*)(dst + 8) = o1;
}

// ---------------- main: barrier-free per-wave implicit GEMM
// Each wave owns 16 positions x all 64 couts. B-fragments blended directly in registers.
__global__ __launch_bounds__(256, 4) void dcn_mfma(
    const unsigned short* __restrict__ xn, const float* __restrict__ off,
    const float* __restrict__ msk, const unsigned short* __restrict__ wA2,
    const float* __restrict__ bias, float* __restrict__ out) {
    __shared__ uintx4 s_meta[Kt * 64];        // {wp01, wp23, o00|o01<<16, o10|o11<<16}

    const int t = threadIdx.x;
    int blk = blockIdx.x;
    blk = (blk & 7) * 256 + (blk >> 3);       // XCD-chunked swizzle (2048 = 8*256)
    const int b = blk >> 8;
    const int ho = (blk & 255) >> 1;
    const int w0 = (blk & 1) * 64;

    const int wv = t >> 6;                    // wave id: positions [16wv, 16wv+16)
    const int l = t & 63;

    // ---- meta precompute (cooperative): bf16 weights (mask+valid folded) + corner indices
    for (int idx = t; idx < Kt * 64; idx += 256) {
        const int k = idx >> 6, pp = idx & 63;
        const int kh = k / 3, kw = k - kh * 3;
        const int wo = w0 + pp;
        const size_t obase = ((size_t)b * 18 + 2 * k) * 16384 + ho * 128 + wo;
        const float oy = off[obase];
        const float ox = off[obase + 16384];
        const float m = msk[((size_t)b * 9 + k) * 16384 + ho * 128 + wo];
        const float py = (float)(ho - 1 + kh) + oy;
        const float px = (float)(wo - 1 + kw) + ox;
        const float y0f = floorf(py), x0f = floorf(px);
        const int iy0 = (int)y0f, ix0 = (int)x0f;
        const float wy = py - y0f, wx = px - x0f;
        const int iy1 = iy0 + 1, ix1 = ix0 + 1;
        const bool vy0 = ((unsigned)iy0 < 128u), vy1 = ((unsigned)iy1 < 128u);
        const bool vx0 = ((unsigned)ix0 < 128u), vx1 = ((unsigned)ix1 < 128u);
        const float w00 = (1.f - wy) * (1.f - wx) * m * ((vy0 && vx0) ? 1.f : 0.f);
        const float w01 = (1.f - wy) * wx * m * ((vy0 && vx1) ? 1.f : 0.f);
        const float w10 = wy * (1.f - wx) * m * ((vy1 && vx0) ? 1.f : 0.f);
        const float w11 = wy * wx * m * ((vy1 && vx1) ? 1.f : 0.f);
        const int cy0 = min(max(iy0, 0), 127), cy1 = min(max(iy1, 0), 127);
        const int cx0 = min(max(ix0, 0), 127), cx1 = min(max(ix1, 0), 127);
        const unsigned o00 = (unsigned)(cy0 * 128 + cx0), o01 = (unsigned)(cy0 * 128 + cx1);
        const unsigned o10 = (unsigned)(cy1 * 128 + cx0), o11 = (unsigned)(cy1 * 128 + cx1);
        uintx4 mt;
        mt.x = cvtpk(w00, w01);
        mt.y = cvtpk(w10, w11);
        mt.z = o00 | (o01 << 16);
        mt.w = o10 | (o11 << 16);
        s_meta[idx] = mt;
    }
    __syncthreads();   // meta ready — the ONLY barrier; main loop below is barrier-free

    floatx4 acc[4] = {};

    const char* xbase = (const char*)(xn + (size_t)b * (128 * 128 * 64));
    const unsigned chb = ((unsigned)(l >> 4)) * 16u;     // channel sub-block byte offset
    const uintx4* mbase = &s_meta[wv * 16 + (l & 15)];   // + k*64 per tap
    const unsigned short* abase = wA2 + (size_t)l * 8;   // + (k*8 + h*4 + g)*512

    #pragma unroll 1
    for (int k = 0; k < Kt; ++k) {
        const uintx4 mt = mbase[k * 64];
        const unsigned wp01 = mt.x, wp23 = mt.y;
        const unsigned f00 = ((mt.z & 0xffffu) << 7) + chb;
        const unsigned f01 = ((mt.z >> 16) << 7) + chb;
        const unsigned f10 = ((mt.w & 0xffffu) << 7) + chb;
        const unsigned f11 = ((mt.w >> 16) << 7) + chb;
        // 8 scattered 16B gathers: 4 corners x 2 k-halves, exactly the channels this lane needs
        const uintx4 q00l = *(const uintx4*)(xbase + f00);
        const uintx4 q00h = *(const uintx4*)(xbase + f00 + 64);
        const uintx4 q01l = *(const uintx4*)(xbase + f01);
        const uintx4 q01h = *(const uintx4*)(xbase + f01 + 64);
        const uintx4 q10l = *(const uintx4*)(xbase + f10);
        const uintx4 q10h = *(const uintx4*)(xbase + f10 + 64);
        const uintx4 q11l = *(const uintx4*)(xbase + f11);
        const uintx4 q11h = *(const uintx4*)(xbase + f11 + 64);
        // 8 coalesced A-fragment loads (1KB/inst, L1/L2-hot)
        const unsigned short* ak = abase + k * 4096;
        short8 a[8];                                    // [h*4+g]
        #pragma unroll
        for (int i = 0; i < 8; ++i) a[i] = *(const short8*)(ak + i * 512);
        // blend -> B-fragments in registers (no LDS)
        uintx4 v0, v1;
        #pragma unroll
        for (int j = 0; j < 4; ++j) {
            const unsigned pa = __builtin_amdgcn_perm(q01l[j], q00l[j], 0x05040100u);
            const unsigned pb = __builtin_amdgcn_perm(q11l[j], q10l[j], 0x05040100u);
            const unsigned pc = __builtin_amdgcn_perm(q01l[j], q00l[j], 0x07060302u);
            const unsigned pd = __builtin_amdgcn_perm(q11l[j], q10l[j], 0x07060302u);
            const float f0 = dot2bf(pa, wp01, dot2bf(pb, wp23, 0.f));
            const float f1 = dot2bf(pc, wp01, dot2bf(pd, wp23, 0.f));
            v0[j] = cvtpk(f0, f1);
        }
        #pragma unroll
        for (int j = 0; j < 4; ++j) {
            const unsigned pa = __builtin_amdgcn_perm(q01h[j], q00h[j], 0x05040100u);
            const unsigned pb = __builtin_amdgcn_perm(q11h[j], q10h[j], 0x05040100u);
            const unsigned pc = __builtin_amdgcn_perm(q01h[j], q00h[j], 0x07060302u);
            const unsigned pd = __builtin_amdgcn_perm(q11h[j], q10h[j], 0x07060302u);
            const float f0 = dot2bf(pa, wp01, dot2bf(pb, wp23, 0.f));
            const float f1 = dot2bf(pc, wp01, dot2bf(pd, wp23, 0.f));
            v1[j] = cvtpk(f0, f1);
        }
        const short8 b0 = *(const short8*)&v0;
        const short8 b1 = *(const short8*)&v1;
        #pragma unroll
        for (int g = 0; g < 4; ++g) {
            acc[g] = __builtin_amdgcn_mfma_f32_16x16x32_bf16(a[g], b0, acc[g], 0, 0, 0);
            acc[g] = __builtin_amdgcn_mfma_f32_16x16x32_bf16(a[4 + g], b1, acc[g], 0, 0, 0);
        }
    }

    // ---- epilogue: +bias, ReLU6 (C/D: col=lane&15 -> position, row=(lane>>4)*4+r -> cout)
    #pragma unroll
    for (int g = 0; g < 4; ++g) {
        #pragma unroll
        for (int r = 0; r < 4; ++r) {
            const int co = g * 16 + (l >> 4) * 4 + r;
            float v = acc[g][r] + bias[co];
            v = fminf(fmaxf(v, 0.f), 6.f);
            out[(((size_t)b * 64 + co) * 128 + ho) * 128 + w0 + wv * 16 + (l & 15)] = v;
        }
    }
}

// ================= fallback fp32 path for small ws_size =================
constexpr int NT = 64;
constexpr int LDSS = 68;

__global__ void reorder_weight(const float* __restrict__ w, float* __restrict__ wT) {
    int i = blockIdx.x * blockDim.x + threadIdx.x;
    if (i >= Cout * Cin * Kt) return;
    int o = i / (Cin * Kt);
    int r = i % (Cin * Kt);
    int c = r / Kt;
    int k = r % Kt;
    wT[(k * Cin + c) * Cout + o] = w[i];
}

__global__ __launch_bounds__(256, 4) void dcn_kernel(
    const float* __restrict__ in, const float* __restrict__ off,
    const float* __restrict__ msk, const float* __restrict__ wT,
    const float* __restrict__ bias, float* __restrict__ out) {
    __shared__ float s_w[Cin * LDSS];
    __shared__ float s_s[Cin * LDSS];
    const int tid = threadIdx.x;
    const int blk = blockIdx.x;
    const int b = blk >> 8;
    const int ho = (blk & 255) >> 1;
    const int w0 = (blk & 1) * NT;
    const int lane = tid & 63;
    const int c4 = tid >> 6;
    const int ty = tid >> 4;
    const int tx = tid & 15;
    const float* in_b = in + b * (Cin * Hh * Ww);
    const int wo = w0 + lane;
    float acc[4][4];
    #pragma unroll
    for (int i = 0; i < 4; ++i)
        #pragma unroll
        for (int j = 0; j < 4; ++j) acc[i][j] = 0.f;
    for (int k = 0; k < Kt; ++k) {
        {
            const float* src = wT + k * (Cin * Cout);
            const int c = tid >> 2;
            const int g = tid & 3;
            const float4* s = (const float4*)(src + c * Cout + g * 16);
            float4* dq = (float4*)(&s_w[c * LDSS + g * 16]);
            dq[0] = s[0]; dq[1] = s[1]; dq[2] = s[2]; dq[3] = s[3];
        }
        {
            const int kh = k / 3, kw = k % 3;
            const float oy = off[(((size_t)b * 2 * Kt + 2 * k) * Ho + ho) * Wo + wo];
            const float ox = off[(((size_t)b * 2 * Kt + 2 * k + 1) * Ho + ho) * Wo + wo];
            const float m = msk[(((size_t)b * Kt + k) * Ho + ho) * Wo + wo];
            const float py = (float)(ho - 1 + kh) + oy;
            const float px = (float)(wo - 1 + kw) + ox;
            const float y0f = floorf(py), x0f = floorf(px);
            const int iy0 = (int)y0f, ix0 = (int)x0f;
            const float wy = py - y0f, wx = px - x0f;
            const int iy1 = iy0 + 1, ix1 = ix0 + 1;
            const bool vy0 = (iy0 >= 0) & (iy0 < Hh);
            const bool vy1 = (iy1 >= 0) & (iy1 < Hh);
            const bool vx0 = (ix0 >= 0) & (ix0 < Ww);
            const bool vx1 = (ix1 >= 0) & (ix1 < Ww);
            const int cy0 = min(max(iy0, 0), Hh - 1), cy1 = min(max(iy1, 0), Hh - 1);
            const int cx0 = min(max(ix0, 0), Ww - 1), cx1 = min(max(ix1, 0), Ww - 1);
            const float w00 = (1.f - wy) * (1.f - wx) * m * ((vy0 & vx0) ? 1.f : 0.f);
            const float w01 = (1.f - wy) * wx * m * ((vy0 & vx1) ? 1.f : 0.f);
            const float w10 = wy * (1.f - wx) * m * ((vy1 & vx0) ? 1.f : 0.f);
            const float w11 = wy * wx * m * ((vy1 & vx1) ? 1.f : 0.f);
            const int o00 = cy0 * Ww + cx0, o01 = cy0 * Ww + cx1;
            const int o10 = cy1 * Ww + cx0, o11 = cy1 * Ww + cx1;
            const float* pp = in_b + (c4 * 16) * (Hh * Ww);
            #pragma unroll
            for (int ii = 0; ii < 16; ++ii) {
                float v = pp[o00] * w00 + pp[o01] * w01 + pp[o10] * w10 + pp[o11] * w11;
                s_s[(c4 * 16 + ii) * LDSS + lane] = v;
                pp += Hh * Ww;
            }
        }
        __syncthreads();
        #pragma unroll 8
        for (int c = 0; c < Cin; ++c) {
            const float4 a = *(const float4*)(&s_w[c * LDSS + ty * 4]);
            const float4 bv = *(const float4*)(&s_s[c * LDSS + tx * 4]);
            const float* ap = (const float*)&a;
            const float* bp = (const float*)&bv;
            #pragma unroll
            for (int i = 0; i < 4; ++i)
                #pragma unroll
                for (int j = 0; j < 4; ++j) acc[i][j] += ap[i] * bp[j];
        }
        __syncthreads();
    }
    #pragma unroll
    for (int i = 0; i < 4; ++i) {
        const int co = ty * 4 + i;
        const float bs = bias[co];
        float4 r;
        float* rp = (float*)&r;
        #pragma unroll
        for (int j = 0; j < 4; ++j) {
            float v = acc[i][j] + bs;
            v = fminf(fmaxf(v, 0.f), 6.f);
            rp[j] = v;
        }
        *(float4*)(&out[(((size_t)b * Cout + co) * Ho + ho) * Wo + w0 + tx * 4]) = r;
    }
}

extern "C" void kernel_launch(void* const* d_in, const int* in_sizes, int n_in,
                              void* d_out, int out_size, void* d_ws, size_t ws_size,
                              hipStream_t stream) {
    const float* in = (const float*)d_in[0];
    const float* off = (const float*)d_in[1];
    const float* msk = (const float*)d_in[2];
    const float* w = (const float*)d_in[3];
    const float* bias = (const float*)d_in[4];
    float* out = (float*)d_out;

    const size_t needX = (size_t)8 * 128 * 128 * 64 * 2;   // 16 MB NHWC bf16
    const size_t xoff = 131072;                            // wA2 region (73728 B used)
    if (ws_size >= xoff + needX) {
        unsigned short* wAb = (unsigned short*)d_ws;
        unsigned short* xnb = (unsigned short*)((char*)d_ws + xoff);
        prep_w<<<144, 256, 0, stream>>>(w, wAb);
        to_nhwc<<<2048, 256, 0, stream>>>(in, xnb);
        dcn_mfma<<<2048, 256, 0, stream>>>(xnb, off, msk, wAb, bias, out);
    } else {
        float* wT = (float*)d_ws;                          // 147456 B
        reorder_weight<<<(Cout * Cin * Kt + 255) / 256, 256, 0, stream>>>(w, wT);
        dcn_kernel<<<(B * Ho * Wo) / NT, 256, 0, stream>>>(in, off, msk, wT, bias, out);
    }
}

// Round 10
// 61.222 us; speedup vs baseline: 1.8058x; 1.8058x over previous
//
#include <hip/hip_runtime.h>

typedef __attribute__((ext_vector_type(8))) short short8;
typedef __attribute__((ext_vector_type(8))) unsigned short ushort8;
typedef __attribute__((ext_vector_type(4))) float floatx4;
typedef __attribute__((ext_vector_type(4))) unsigned int uintx4;

constexpr int B = 8, Cin = 64, Hh = 128, Ww = 128, Cout = 64, Kt = 9, Ho = 128, Wo = 128;

__device__ __forceinline__ unsigned short f2bf(float f) {
    unsigned int u = __float_as_uint(f);
    unsigned int r = (u + 0x7fffu + ((u >> 16) & 1u)) >> 16;   // RTNE
    return (unsigned short)r;
}
__device__ __forceinline__ unsigned int cvtpk(float lo, float hi) {
    unsigned int r;
    asm("v_cvt_pk_bf16_f32 %0, %1, %2" : "=v"(r) : "v"(lo), "v"(hi));
    return r;
}
__device__ __forceinline__ float dot2bf(unsigned int a, unsigned int b, float c) {
    float d;
    asm("v_dot2_f32_bf16 %0, %1, %2, %3" : "=v"(d) : "v"(a), "v"(b), "v"(c));
    return d;
}

// ---------------- prep: weight -> A-fragment-friendly [cout][tap*64+c] bf16
__global__ void prep_w(const float* __restrict__ w, unsigned short* __restrict__ wA) {
    int i = blockIdx.x * 256 + threadIdx.x;           // over Cout*Cin*Kt = 36864
    if (i >= Cout * Cin * Kt) return;
    int o = i / (Cin * Kt);
    int r = i % (Cin * Kt);
    int c = r / Kt;
    int k = r % Kt;
    wA[o * 576 + k * 64 + c] = f2bf(w[i]);
}

// ---------------- prep: NCHW fp32 -> NHWC bf16
__global__ __launch_bounds__(256) void to_nhwc(const float* __restrict__ in,
                                               unsigned short* __restrict__ xn) {
    __shared__ float s[64 * 65];
    const int t = threadIdx.x;
    const int blk = blockIdx.x;               // b*256 + y*2 + xh
    const int b = blk >> 8;
    const int y = (blk & 255) >> 1;
    const int x0 = (blk & 1) * 64;
    const float* src = in + ((size_t)(b * 64) * 128 + y) * 128 + x0;  // in[b][0][y][x0]
    #pragma unroll
    for (int i = 0; i < 16; ++i) {
        int c = i * 4 + (t >> 6);
        s[c * 65 + (t & 63)] = src[(size_t)c * 16384 + (t & 63)];
    }
    __syncthreads();
    const int x = t >> 2, c0 = (t & 3) * 16;
    ushort8 o0, o1;
    #pragma unroll
    for (int j = 0; j < 8; ++j) {
        o0[j] = f2bf(s[(c0 + j) * 65 + x]);
        o1[j] = f2bf(s[(c0 + 8 + j) * 65 + x]);
    }
    unsigned short* dst = xn + (((size_t)(b * 128 + y) * 128 + x0 + x) * 64 + c0);
    *(ushort8*)dst = o0;
    *(ushort8*)(dst + 8) = o1;
}

// gathered corner data for one tap (consumed before the next barrier — never crosses one)
struct Gath {
    uintx4 q0, q1, q2, q3, q4, q5, q6, q7;   // 00a,00b,01a,01b,10a,10b,11a,11b
    unsigned wp01, wp23;
};

// ---------------- main: implicit-GEMM DCNv2, two taps per barrier interval
__global__ __launch_bounds__(256) void dcn_mfma(
    const unsigned short* __restrict__ xn, const float* __restrict__ off,
    const float* __restrict__ msk, const unsigned short* __restrict__ wA,
    const float* __restrict__ bias, float* __restrict__ out) {
    __shared__ uintx4 s_meta[Kt * 64];          // {wp01, wp23, o00|o01<<16, o10|o11<<16}
    __shared__ unsigned short s_b[2][64 * 64];  // two tap-slots per interval (swizzled)

    const int t = threadIdx.x;
    int blk = blockIdx.x;
    blk = (blk & 7) * 256 + (blk >> 3);       // XCD-chunked swizzle (2048 = 8*256)
    const int b = blk >> 8;
    const int ho = (blk & 255) >> 1;
    const int w0 = (blk & 1) * 64;

    const int wv = t >> 6;                    // wave id: couts [16wv, 16wv+16)
    const int l = t & 63;
    const int p = t >> 2;                     // sampling: position
    const int cg = t & 3;                     // sampling: channel group (16 ch)

    // ---- meta precompute (cooperative): bf16 weights (mask+valid folded) + corner indices
    for (int idx = t; idx < Kt * 64; idx += 256) {
        const int k = idx >> 6, pp = idx & 63;
        const int kh = k / 3, kw = k - kh * 3;
        const int wo = w0 + pp;
        const size_t obase = ((size_t)b * 18 + 2 * k) * 16384 + ho * 128 + wo;
        const float oy = off[obase];
        const float ox = off[obase + 16384];
        const float m = msk[((size_t)b * 9 + k) * 16384 + ho * 128 + wo];
        const float py = (float)(ho - 1 + kh) + oy;
        const float px = (float)(wo - 1 + kw) + ox;
        const float y0f = floorf(py), x0f = floorf(px);
        const int iy0 = (int)y0f, ix0 = (int)x0f;
        const float wy = py - y0f, wx = px - x0f;
        const int iy1 = iy0 + 1, ix1 = ix0 + 1;
        const bool vy0 = ((unsigned)iy0 < 128u), vy1 = ((unsigned)iy1 < 128u);
        const bool vx0 = ((unsigned)ix0 < 128u), vx1 = ((unsigned)ix1 < 128u);
        const float w00 = (1.f - wy) * (1.f - wx) * m * ((vy0 && vx0) ? 1.f : 0.f);
        const float w01 = (1.f - wy) * wx * m * ((vy0 && vx1) ? 1.f : 0.f);
        const float w10 = wy * (1.f - wx) * m * ((vy1 && vx0) ? 1.f : 0.f);
        const float w11 = wy * wx * m * ((vy1 && vx1) ? 1.f : 0.f);
        const int cy0 = min(max(iy0, 0), 127), cy1 = min(max(iy1, 0), 127);
        const int cx0 = min(max(ix0, 0), 127), cx1 = min(max(ix1, 0), 127);
        const unsigned o00 = (unsigned)(cy0 * 128 + cx0), o01 = (unsigned)(cy0 * 128 + cx1);
        const unsigned o10 = (unsigned)(cy1 * 128 + cx0), o11 = (unsigned)(cy1 * 128 + cx1);
        uintx4 mt;
        mt.x = cvtpk(w00, w01);
        mt.y = cvtpk(w10, w11);
        mt.z = o00 | (o01 << 16);
        mt.w = o10 | (o11 << 16);
        s_meta[idx] = mt;
    }

    floatx4 acc[4] = {};

    // hoisted per-thread constants
    const unsigned short* wbase = wA + (16 * wv + (l & 15)) * 576 + (l >> 4) * 8;
    const char* xbase = (const char*)(xn + (size_t)b * (128 * 128 * 64));
    const unsigned cgb = (unsigned)cg * 32u;    // channel-group byte offset
    const int ckA = (cg * 2) ^ (p & 7);
    const int ckB = (cg * 2 + 1) ^ (p & 7);
    const int wrA = p * 64 + ckA * 8;
    const int wrB = p * 64 + ckB * 8;
    int rdo[8];
    #pragma unroll
    for (int h = 0; h < 2; ++h)
        #pragma unroll
        for (int f = 0; f < 4; ++f) {
            const int pp = 16 * f + (l & 15);
            const int ck = (h * 4 + (l >> 4)) ^ (pp & 7);
            rdo[h * 4 + f] = pp * 64 + ck * 8;
        }

    __syncthreads();   // meta ready

    // ---- issue gathers for tap k (wave-uniform base + 32-bit voffset); read-only data
    auto issue = [&](int k) -> Gath {
        Gath g;
        const uintx4 mt = s_meta[k * 64 + p];
        g.wp01 = mt.x;
        g.wp23 = mt.y;
        const unsigned f00 = ((mt.z & 0xffffu) << 7) + cgb;
        const unsigned f01 = ((mt.z >> 16) << 7) + cgb;
        const unsigned f10 = ((mt.w & 0xffffu) << 7) + cgb;
        const unsigned f11 = ((mt.w >> 16) << 7) + cgb;
        const uintx4* c00 = (const uintx4*)(xbase + f00);
        const uintx4* c01 = (const uintx4*)(xbase + f01);
        const uintx4* c10 = (const uintx4*)(xbase + f10);
        const uintx4* c11 = (const uintx4*)(xbase + f11);
        g.q0 = c00[0]; g.q1 = c00[1];
        g.q2 = c01[0]; g.q3 = c01[1];
        g.q4 = c10[0]; g.q5 = c10[1];
        g.q6 = c11[0]; g.q7 = c11[1];
        return g;
    };
    // ---- blend + LDS write into tap-slot `slot` (round-3 addresses within the slot)
    auto blend_write = [&](int slot, const Gath& g) {
        uintx4 vA, vB;
        #pragma unroll
        for (int j = 0; j < 4; ++j) {
            const unsigned pa = __builtin_amdgcn_perm(g.q2[j], g.q0[j], 0x05040100u);
            const unsigned pb = __builtin_amdgcn_perm(g.q6[j], g.q4[j], 0x05040100u);
            const unsigned pc = __builtin_amdgcn_perm(g.q2[j], g.q0[j], 0x07060302u);
            const unsigned pd = __builtin_amdgcn_perm(g.q6[j], g.q4[j], 0x07060302u);
            const float f0 = dot2bf(pa, g.wp01, dot2bf(pb, g.wp23, 0.f));
            const float f1 = dot2bf(pc, g.wp01, dot2bf(pd, g.wp23, 0.f));
            vA[j] = cvtpk(f0, f1);
        }
        #pragma unroll
        for (int j = 0; j < 4; ++j) {
            const unsigned pa = __builtin_amdgcn_perm(g.q3[j], g.q1[j], 0x05040100u);
            const unsigned pb = __builtin_amdgcn_perm(g.q7[j], g.q5[j], 0x05040100u);
            const unsigned pc = __builtin_amdgcn_perm(g.q3[j], g.q1[j], 0x07060302u);
            const unsigned pd = __builtin_amdgcn_perm(g.q7[j], g.q5[j], 0x07060302u);
            const float f0 = dot2bf(pa, g.wp01, dot2bf(pb, g.wp23, 0.f));
            const float f1 = dot2bf(pc, g.wp01, dot2bf(pd, g.wp23, 0.f));
            vB[j] = cvtpk(f0, f1);
        }
        *(uintx4*)&s_b[slot][wrA] = vA;
        *(uintx4*)&s_b[slot][wrB] = vB;
    };
    // ---- MFMA one tap from slot
    auto mfma_tap = [&](int slot, int k) {
        const short8 a0 = *(const short8*)(wbase + k * 64);
        const short8 a1 = *(const short8*)(wbase + k * 64 + 32);
        #pragma unroll
        for (int h = 0; h < 2; ++h) {
            const short8 a = h ? a1 : a0;
            #pragma unroll
            for (int f = 0; f < 4; ++f) {
                const short8 bfrag = *(const short8*)&s_b[slot][rdo[h * 4 + f]];
                acc[f] = __builtin_amdgcn_mfma_f32_16x16x32_bf16(a, bfrag, acc[f], 0, 0, 0);
            }
        }
    };

    // ---- main loop: two taps per barrier interval; nothing lives across a barrier
    for (int j = 0; j < 5; ++j) {
        const int k0 = 2 * j;
        const bool has2 = (k0 + 1 < Kt);
        Gath ga = issue(k0);
        Gath gb;
        if (has2) gb = issue(k0 + 1);          // both taps' loads in flight together
        blend_write(0, ga);
        if (has2) blend_write(1, gb);
        __syncthreads();                       // writes visible
        mfma_tap(0, k0);
        if (has2) mfma_tap(1, k0 + 1);
        if (j < 4) __syncthreads();            // reads done before next interval's writes
    }

    // ---- epilogue: +bias, ReLU6
    #pragma unroll
    for (int f = 0; f < 4; ++f) {
        #pragma unroll
        for (int r = 0; r < 4; ++r) {
            const int co = 16 * wv + (l >> 4) * 4 + r;
            float v = acc[f][r] + bias[co];
            v = fminf(fmaxf(v, 0.f), 6.f);
            out[(((size_t)b * 64 + co) * 128 + ho) * 128 + w0 + 16 * f + (l & 15)] = v;
        }
    }
}

// ================= fallback fp32 path for small ws_size =================
constexpr int NT = 64;
constexpr int LDSS = 68;

__global__ void reorder_weight(const float* __restrict__ w, float* __restrict__ wT) {
    int i = blockIdx.x * blockDim.x + threadIdx.x;
    if (i >= Cout * Cin * Kt) return;
    int o = i / (Cin * Kt);
    int r = i % (Cin * Kt);
    int c = r / Kt;
    int k = r % Kt;
    wT[(k * Cin + c) * Cout + o] = w[i];
}

__global__ __launch_bounds__(256, 4) void dcn_kernel(
    const float* __restrict__ in, const float* __restrict__ off,
    const float* __restrict__ msk, const float* __restrict__ wT,
    const float* __restrict__ bias, float* __restrict__ out) {
    __shared__ float s_w[Cin * LDSS];
    __shared__ float s_s[Cin * LDSS];
    const int tid = threadIdx.x;
    const int blk = blockIdx.x;
    const int b = blk >> 8;
    const int ho = (blk & 255) >> 1;
    const int w0 = (blk & 1) * NT;
    const int lane = tid & 63;
    const int c4 = tid >> 6;
    const int ty = tid >> 4;
    const int tx = tid & 15;
    const float* in_b = in + b * (Cin * Hh * Ww);
    const int wo = w0 + lane;
    float acc[4][4];
    #pragma unroll
    for (int i = 0; i < 4; ++i)
        #pragma unroll
        for (int j = 0; j < 4; ++j) acc[i][j] = 0.f;
    for (int k = 0; k < Kt; ++k) {
        {
            const float* src = wT + k * (Cin * Cout);
            const int c = tid >> 2;
            const int g = tid & 3;
            const float4* s = (const float4*)(src + c * Cout + g * 16);
            float4* dq = (float4*)(&s_w[c * LDSS + g * 16]);
            dq[0] = s[0]; dq[1] = s[1]; dq[2] = s[2]; dq[3] = s[3];
        }
        {
            const int kh = k / 3, kw = k % 3;
            const float oy = off[(((size_t)b * 2 * Kt + 2 * k) * Ho + ho) * Wo + wo];
            const float ox = off[(((size_t)b * 2 * Kt + 2 * k + 1) * Ho + ho) * Wo + wo];
            const float m = msk[(((size_t)b * Kt + k) * Ho + ho) * Wo + wo];
            const float py = (float)(ho - 1 + kh) + oy;
            const float px = (float)(wo - 1 + kw) + ox;
            const float y0f = floorf(py), x0f = floorf(px);
            const int iy0 = (int)y0f, ix0 = (int)x0f;
            const float wy = py - y0f, wx = px - x0f;
            const int iy1 = iy0 + 1, ix1 = ix0 + 1;
            const bool vy0 = (iy0 >= 0) & (iy0 < Hh);
            const bool vy1 = (iy1 >= 0) & (iy1 < Hh);
            const bool vx0 = (ix0 >= 0) & (ix0 < Ww);
            const bool vx1 = (ix1 >= 0) & (ix1 < Ww);
            const int cy0 = min(max(iy0, 0), Hh - 1), cy1 = min(max(iy1, 0), Hh - 1);
            const int cx0 = min(max(ix0, 0), Ww - 1), cx1 = min(max(ix1, 0), Ww - 1);
            const float w00 = (1.f - wy) * (1.f - wx) * m * ((vy0 & vx0) ? 1.f : 0.f);
            const float w01 = (1.f - wy) * wx * m * ((vy0 & vx1) ? 1.f : 0.f);
            const float w10 = wy * (1.f - wx) * m * ((vy1 & vx0) ? 1.f : 0.f);
            const float w11 = wy * wx * m * ((vy1 & vx1) ? 1.f : 0.f);
            const int o00 = cy0 * Ww + cx0, o01 = cy0 * Ww + cx1;
            const int o10 = cy1 * Ww + cx0, o11 = cy1 * Ww + cx1;
            const float* pp = in_b + (c4 * 16) * (Hh * Ww);
            #pragma unroll
            for (int ii = 0; ii < 16; ++ii) {
                float v = pp[o00] * w00 + pp[o01] * w01 + pp[o10] * w10 + pp[o11] * w11;
                s_s[(c4 * 16 + ii) * LDSS + lane] = v;
                pp += Hh * Ww;
            }
        }
        __syncthreads();
        #pragma unroll 8
        for (int c = 0; c < Cin; ++c) {
            const float4 a = *(const float4*)(&s_w[c * LDSS + ty * 4]);
            const float4 bv = *(const float4*)(&s_s[c * LDSS + tx * 4]);
            const float* ap = (const float*)&a;
            const float* bp = (const float*)&bv;
            #pragma unroll
            for (int i = 0; i < 4; ++i)
                #pragma unroll
                for (int j = 0; j < 4; ++j) acc[i][j] += ap[i] * bp[j];
        }
        __syncthreads();
    }
    #pragma unroll
    for (int i = 0; i < 4; ++i) {
        const int co = ty * 4 + i;
        const float bs = bias[co];
        float4 r;
        float* rp = (float*)&r;
        #pragma unroll
        for (int j = 0; j < 4; ++j) {
            float v = acc[i][j] + bs;
            v = fminf(fmaxf(v, 0.f), 6.f);
            rp[j] = v;
        }
        *(float4*)(&out[(((size_t)b * Cout + co) * Ho + ho) * Wo + w0 + tx * 4]) = r;
    }
}

extern "C" void kernel_launch(void* const* d_in, const int* in_sizes, int n_in,
                              void* d_out, int out_size, void* d_ws, size_t ws_size,
                              hipStream_t stream) {
    const float* in = (const float*)d_in[0];
    const float* off = (const float*)d_in[1];
    const float* msk = (const float*)d_in[2];
    const float* w = (const float*)d_in[3];
    const float* bias = (const float*)d_in[4];
    float* out = (float*)d_out;

    const size_t needX = (size_t)8 * 128 * 128 * 64 * 2;   // 16 MB NHWC bf16
    const size_t xoff = 131072;                            // wA region (73728 B used)
    if (ws_size >= xoff + needX) {
        unsigned short* wAb = (unsigned short*)d_ws;
        unsigned short* xnb = (unsigned short*)((char*)d_ws + xoff);
        prep_w<<<144, 256, 0, stream>>>(w, wAb);
        to_nhwc<<<2048, 256, 0, stream>>>(in, xnb);
        dcn_mfma<<<2048, 256, 0, stream>>>(xnb, off, msk, wAb, bias, out);
    } else {
        float* wT = (float*)d_ws;                          // 147456 B
        reorder_weight<<<(Cout * Cin * Kt + 255) / 256, 256, 0, stream>>>(w, wT);
        dcn_kernel<<<(B * Ho * Wo) / NT, 256, 0, stream>>>(in, off, msk, wT, bias, out);
    }
}

// Round 11
// 60.451 us; speedup vs baseline: 1.8288x; 1.0128x over previous
//
#include <hip/hip_runtime.h>

typedef __attribute__((ext_vector_type(8))) short short8;
typedef __attribute__((ext_vector_type(8))) unsigned short ushort8;
typedef __attribute__((ext_vector_type(4))) float floatx4;
typedef __attribute__((ext_vector_type(4))) unsigned int uintx4;

constexpr int B = 8, Cin = 64, Hh = 128, Ww = 128, Cout = 64, Kt = 9, Ho = 128, Wo = 128;

__device__ __forceinline__ unsigned short f2bf(float f) {
    unsigned int u = __float_as_uint(f);
    unsigned int r = (u + 0x7fffu + ((u >> 16) & 1u)) >> 16;   // RTNE
    return (unsigned short)r;
}
__device__ __forceinline__ unsigned int cvtpk(float lo, float hi) {
    unsigned int r;
    asm("v_cvt_pk_bf16_f32 %0, %1, %2" : "=v"(r) : "v"(lo), "v"(hi));
    return r;
}
__device__ __forceinline__ float dot2bf(unsigned int a, unsigned int b, float c) {
    float d;
    asm("v_dot2_f32_bf16 %0, %1, %2, %3" : "=v"(d) : "v"(a), "v"(b), "v"(c));
    return d;
}

// ---------------- prep: weight -> A-fragment-friendly [cout][tap*64+c] bf16
__global__ void prep_w(const float* __restrict__ w, unsigned short* __restrict__ wA) {
    int i = blockIdx.x * 256 + threadIdx.x;           // over Cout*Cin*Kt = 36864
    if (i >= Cout * Cin * Kt) return;
    int o = i / (Cin * Kt);
    int r = i % (Cin * Kt);
    int c = r / Kt;
    int k = r % Kt;
    wA[o * 576 + k * 64 + c] = f2bf(w[i]);
}

// ---------------- prep: NCHW fp32 -> NHWC bf16
__global__ __launch_bounds__(256) void to_nhwc(const float* __restrict__ in,
                                               unsigned short* __restrict__ xn) {
    __shared__ float s[64 * 65];
    const int t = threadIdx.x;
    const int blk = blockIdx.x;               // b*256 + y*2 + xh
    const int b = blk >> 8;
    const int y = (blk & 255) >> 1;
    const int x0 = (blk & 1) * 64;
    const float* src = in + ((size_t)(b * 64) * 128 + y) * 128 + x0;  // in[b][0][y][x0]
    #pragma unroll
    for (int i = 0; i < 16; ++i) {
        int c = i * 4 + (t >> 6);
        s[c * 65 + (t & 63)] = src[(size_t)c * 16384 + (t & 63)];
    }
    __syncthreads();
    const int x = t >> 2, c0 = (t & 3) * 16;
    ushort8 o0, o1;
    #pragma unroll
    for (int j = 0; j < 8; ++j) {
        o0[j] = f2bf(s[(c0 + j) * 65 + x]);
        o1[j] = f2bf(s[(c0 + 8 + j) * 65 + x]);
    }
    unsigned short* dst = xn + (((size_t)(b * 128 + y) * 128 + x0 + x) * 64 + c0);
    *(ushort8*)dst = o0;
    *(ushort8*)(dst + 8) = o1;
}

// gathered corner data for one tap (consumed before the next barrier — never crosses one)
struct Gath {
    uintx4 q0, q1, q2, q3, q4, q5, q6, q7;   // 00a,00b,01a,01b,10a,10b,11a,11b
    unsigned wp01, wp23;
};

// ---------------- main: implicit-GEMM DCNv2, two taps per barrier interval
// Gather geometry: thread (p, cg) reads 16B chunk cg of line 0 (+cg*16) and chunk cg of
// line 1 (+64+cg*16) of each 128B channel record — each wave gather inst is a fully
// line-coalesced read (4 lanes per 64B line), halving TA line-services vs the +0/+16 split.
__global__ __launch_bounds__(256) void dcn_mfma(
    const unsigned short* __restrict__ xn, const float* __restrict__ off,
    const float* __restrict__ msk, const unsigned short* __restrict__ wA,
    const float* __restrict__ bias, float* __restrict__ out) {
    __shared__ uintx4 s_meta[Kt * 64];          // {wp01, wp23, o00|o01<<16, o10|o11<<16}
    __shared__ unsigned short s_b[2][64 * 64];  // two tap-slots per interval (swizzled)

    const int t = threadIdx.x;
    int blk = blockIdx.x;
    blk = (blk & 7) * 256 + (blk >> 3);       // XCD-chunked swizzle (2048 = 8*256)
    const int b = blk >> 8;
    const int ho = (blk & 255) >> 1;
    const int w0 = (blk & 1) * 64;

    const int wv = t >> 6;                    // wave id: couts [16wv, 16wv+16)
    const int l = t & 63;
    const int p = t >> 2;                     // sampling: position
    const int cg = t & 3;                     // sampling: channel chunk (8 ch low + 8 ch high)

    // ---- meta precompute (cooperative): bf16 weights (mask+valid folded) + corner indices
    for (int idx = t; idx < Kt * 64; idx += 256) {
        const int k = idx >> 6, pp = idx & 63;
        const int kh = k / 3, kw = k - kh * 3;
        const int wo = w0 + pp;
        const size_t obase = ((size_t)b * 18 + 2 * k) * 16384 + ho * 128 + wo;
        const float oy = off[obase];
        const float ox = off[obase + 16384];
        const float m = msk[((size_t)b * 9 + k) * 16384 + ho * 128 + wo];
        const float py = (float)(ho - 1 + kh) + oy;
        const float px = (float)(wo - 1 + kw) + ox;
        const float y0f = floorf(py), x0f = floorf(px);
        const int iy0 = (int)y0f, ix0 = (int)x0f;
        const float wy = py - y0f, wx = px - x0f;
        const int iy1 = iy0 + 1, ix1 = ix0 + 1;
        const bool vy0 = ((unsigned)iy0 < 128u), vy1 = ((unsigned)iy1 < 128u);
        const bool vx0 = ((unsigned)ix0 < 128u), vx1 = ((unsigned)ix1 < 128u);
        const float w00 = (1.f - wy) * (1.f - wx) * m * ((vy0 && vx0) ? 1.f : 0.f);
        const float w01 = (1.f - wy) * wx * m * ((vy0 && vx1) ? 1.f : 0.f);
        const float w10 = wy * (1.f - wx) * m * ((vy1 && vx0) ? 1.f : 0.f);
        const float w11 = wy * wx * m * ((vy1 && vx1) ? 1.f : 0.f);
        const int cy0 = min(max(iy0, 0), 127), cy1 = min(max(iy1, 0), 127);
        const int cx0 = min(max(ix0, 0), 127), cx1 = min(max(ix1, 0), 127);
        const unsigned o00 = (unsigned)(cy0 * 128 + cx0), o01 = (unsigned)(cy0 * 128 + cx1);
        const unsigned o10 = (unsigned)(cy1 * 128 + cx0), o11 = (unsigned)(cy1 * 128 + cx1);
        uintx4 mt;
        mt.x = cvtpk(w00, w01);
        mt.y = cvtpk(w10, w11);
        mt.z = o00 | (o01 << 16);
        mt.w = o10 | (o11 << 16);
        s_meta[idx] = mt;
    }

    floatx4 acc[4] = {};

    // hoisted per-thread constants
    const unsigned short* wbase = wA + (16 * wv + (l & 15)) * 576 + (l >> 4) * 8;
    const char* xbase = (const char*)(xn + (size_t)b * (128 * 128 * 64));
    const unsigned cgb = (unsigned)cg * 16u;    // 16B chunk offset within line 0
    const int ckA = cg ^ (p & 7);               // low-half chunk (ch 8cg..8cg+8)
    const int ckB = (4 + cg) ^ (p & 7);         // high-half chunk (ch 32+8cg..)
    const int wrA = p * 64 + ckA * 8;
    const int wrB = p * 64 + ckB * 8;
    int rdo[8];
    #pragma unroll
    for (int h = 0; h < 2; ++h)
        #pragma unroll
        for (int f = 0; f < 4; ++f) {
            const int pp = 16 * f + (l & 15);
            const int ck = (h * 4 + (l >> 4)) ^ (pp & 7);
            rdo[h * 4 + f] = pp * 64 + ck * 8;
        }

    __syncthreads();   // meta ready

    // ---- issue gathers for tap k: per corner, one 16B load in line 0 and one in line 1
    auto issue = [&](int k) -> Gath {
        Gath g;
        const uintx4 mt = s_meta[k * 64 + p];
        g.wp01 = mt.x;
        g.wp23 = mt.y;
        const unsigned f00 = ((mt.z & 0xffffu) << 7) + cgb;
        const unsigned f01 = ((mt.z >> 16) << 7) + cgb;
        const unsigned f10 = ((mt.w & 0xffffu) << 7) + cgb;
        const unsigned f11 = ((mt.w >> 16) << 7) + cgb;
        g.q0 = *(const uintx4*)(xbase + f00);
        g.q1 = *(const uintx4*)(xbase + f00 + 64);
        g.q2 = *(const uintx4*)(xbase + f01);
        g.q3 = *(const uintx4*)(xbase + f01 + 64);
        g.q4 = *(const uintx4*)(xbase + f10);
        g.q5 = *(const uintx4*)(xbase + f10 + 64);
        g.q6 = *(const uintx4*)(xbase + f11);
        g.q7 = *(const uintx4*)(xbase + f11 + 64);
        return g;
    };
    // ---- blend + LDS write into tap-slot `slot` (blend math identical to proven R6)
    auto blend_write = [&](int slot, const Gath& g) {
        uintx4 vA, vB;
        #pragma unroll
        for (int j = 0; j < 4; ++j) {
            const unsigned pa = __builtin_amdgcn_perm(g.q2[j], g.q0[j], 0x05040100u);
            const unsigned pb = __builtin_amdgcn_perm(g.q6[j], g.q4[j], 0x05040100u);
            const unsigned pc = __builtin_amdgcn_perm(g.q2[j], g.q0[j], 0x07060302u);
            const unsigned pd = __builtin_amdgcn_perm(g.q6[j], g.q4[j], 0x07060302u);
            const float f0 = dot2bf(pa, g.wp01, dot2bf(pb, g.wp23, 0.f));
            const float f1 = dot2bf(pc, g.wp01, dot2bf(pd, g.wp23, 0.f));
            vA[j] = cvtpk(f0, f1);
        }
        #pragma unroll
        for (int j = 0; j < 4; ++j) {
            const unsigned pa = __builtin_amdgcn_perm(g.q3[j], g.q1[j], 0x05040100u);
            const unsigned pb = __builtin_amdgcn_perm(g.q7[j], g.q5[j], 0x05040100u);
            const unsigned pc = __builtin_amdgcn_perm(g.q3[j], g.q1[j], 0x07060302u);
            const unsigned pd = __builtin_amdgcn_perm(g.q7[j], g.q5[j], 0x07060302u);
            const float f0 = dot2bf(pa, g.wp01, dot2bf(pb, g.wp23, 0.f));
            const float f1 = dot2bf(pc, g.wp01, dot2bf(pd, g.wp23, 0.f));
            vB[j] = cvtpk(f0, f1);
        }
        *(uintx4*)&s_b[slot][wrA] = vA;
        *(uintx4*)&s_b[slot][wrB] = vB;
    };
    // ---- MFMA one tap from slot
    auto mfma_tap = [&](int slot, int k) {
        const short8 a0 = *(const short8*)(wbase + k * 64);
        const short8 a1 = *(const short8*)(wbase + k * 64 + 32);
        #pragma unroll
        for (int h = 0; h < 2; ++h) {
            const short8 a = h ? a1 : a0;
            #pragma unroll
            for (int f = 0; f < 4; ++f) {
                const short8 bfrag = *(const short8*)&s_b[slot][rdo[h * 4 + f]];
                acc[f] = __builtin_amdgcn_mfma_f32_16x16x32_bf16(a, bfrag, acc[f], 0, 0, 0);
            }
        }
    };

    // ---- main loop: two taps per barrier interval; nothing lives across a barrier
    for (int j = 0; j < 5; ++j) {
        const int k0 = 2 * j;
        const bool has2 = (k0 + 1 < Kt);
        Gath ga = issue(k0);
        Gath gb;
        if (has2) gb = issue(k0 + 1);          // both taps' loads in flight together
        blend_write(0, ga);
        if (has2) blend_write(1, gb);
        __syncthreads();                       // writes visible
        mfma_tap(0, k0);
        if (has2) mfma_tap(1, k0 + 1);
        if (j < 4) __syncthreads();            // reads done before next interval's writes
    }

    // ---- epilogue: +bias, ReLU6
    #pragma unroll
    for (int f = 0; f < 4; ++f) {
        #pragma unroll
        for (int r = 0; r < 4; ++r) {
            const int co = 16 * wv + (l >> 4) * 4 + r;
            float v = acc[f][r] + bias[co];
            v = fminf(fmaxf(v, 0.f), 6.f);
            out[(((size_t)b * 64 + co) * 128 + ho) * 128 + w0 + 16 * f + (l & 15)] = v;
        }
    }
}

// ================= fallback fp32 path for small ws_size =================
constexpr int NT = 64;
constexpr int LDSS = 68;

__global__ void reorder_weight(const float* __restrict__ w, float* __restrict__ wT) {
    int i = blockIdx.x * blockDim.x + threadIdx.x;
    if (i >= Cout * Cin * Kt) return;
    int o = i / (Cin * Kt);
    int r = i % (Cin * Kt);
    int c = r / Kt;
    int k = r % Kt;
    wT[(k * Cin + c) * Cout + o] = w[i];
}

__global__ __launch_bounds__(256, 4) void dcn_kernel(
    const float* __restrict__ in, const float* __restrict__ off,
    const float* __restrict__ msk, const float* __restrict__ wT,
    const float* __restrict__ bias, float* __restrict__ out) {
    __shared__ float s_w[Cin * LDSS];
    __shared__ float s_s[Cin * LDSS];
    const int tid = threadIdx.x;
    const int blk = blockIdx.x;
    const int b = blk >> 8;
    const int ho = (blk & 255) >> 1;
    const int w0 = (blk & 1) * NT;
    const int lane = tid & 63;
    const int c4 = tid >> 6;
    const int ty = tid >> 4;
    const int tx = tid & 15;
    const float* in_b = in + b * (Cin * Hh * Ww);
    const int wo = w0 + lane;
    float acc[4][4];
    #pragma unroll
    for (int i = 0; i < 4; ++i)
        #pragma unroll
        for (int j = 0; j < 4; ++j) acc[i][j] = 0.f;
    for (int k = 0; k < Kt; ++k) {
        {
            const float* src = wT + k * (Cin * Cout);
            const int c = tid >> 2;
            const int g = tid & 3;
            const float4* s = (const float4*)(src + c * Cout + g * 16);
            float4* dq = (float4*)(&s_w[c * LDSS + g * 16]);
            dq[0] = s[0]; dq[1] = s[1]; dq[2] = s[2]; dq[3] = s[3];
        }
        {
            const int kh = k / 3, kw = k % 3;
            const float oy = off[(((size_t)b * 2 * Kt + 2 * k) * Ho + ho) * Wo + wo];
            const float ox = off[(((size_t)b * 2 * Kt + 2 * k + 1) * Ho + ho) * Wo + wo];
            const float m = msk[(((size_t)b * Kt + k) * Ho + ho) * Wo + wo];
            const float py = (float)(ho - 1 + kh) + oy;
            const float px = (float)(wo - 1 + kw) + ox;
            const float y0f = floorf(py), x0f = floorf(px);
            const int iy0 = (int)y0f, ix0 = (int)x0f;
            const float wy = py - y0f, wx = px - x0f;
            const int iy1 = iy0 + 1, ix1 = ix0 + 1;
            const bool vy0 = (iy0 >= 0) & (iy0 < Hh);
            const bool vy1 = (iy1 >= 0) & (iy1 < Hh);
            const bool vx0 = (ix0 >= 0) & (ix0 < Ww);
            const bool vx1 = (ix1 >= 0) & (ix1 < Ww);
            const int cy0 = min(max(iy0, 0), Hh - 1), cy1 = min(max(iy1, 0), Hh - 1);
            const int cx0 = min(max(ix0, 0), Ww - 1), cx1 = min(max(ix1, 0), Ww - 1);
            const float w00 = (1.f - wy) * (1.f - wx) * m * ((vy0 & vx0) ? 1.f : 0.f);
            const float w01 = (1.f - wy) * wx * m * ((vy0 & vx1) ? 1.f : 0.f);
            const float w10 = wy * (1.f - wx) * m * ((vy1 & vx0) ? 1.f : 0.f);
            const float w11 = wy * wx * m * ((vy1 & vx1) ? 1.f : 0.f);
            const int o00 = cy0 * Ww + cx0, o01 = cy0 * Ww + cx1;
            const int o10 = cy1 * Ww + cx0, o11 = cy1 * Ww + cx1;
            const float* pp = in_b + (c4 * 16) * (Hh * Ww);
            #pragma unroll
            for (int ii = 0; ii < 16; ++ii) {
                float v = pp[o00] * w00 + pp[o01] * w01 + pp[o10] * w10 + pp[o11] * w11;
                s_s[(c4 * 16 + ii) * LDSS + lane] = v;
                pp += Hh * Ww;
            }
        }
        __syncthreads();
        #pragma unroll 8
        for (int c = 0; c < Cin; ++c) {
            const float4 a = *(const float4*)(&s_w[c * LDSS + ty * 4]);
            const float4 bv = *(const float4*)(&s_s[c * LDSS + tx * 4]);
            const float* ap = (const float*)&a;
            const float* bp = (const float*)&bv;
            #pragma unroll
            for (int i = 0; i < 4; ++i)
                #pragma unroll
                for (int j = 0; j < 4; ++j) acc[i][j] += ap[i] * bp[j];
        }
        __syncthreads();
    }
    #pragma unroll
    for (int i = 0; i < 4; ++i) {
        const int co = ty * 4 + i;
        const float bs = bias[co];
        float4 r;
        float* rp = (float*)&r;
        #pragma unroll
        for (int j = 0; j < 4; ++j) {
            float v = acc[i][j] + bs;
            v = fminf(fmaxf(v, 0.f), 6.f);
            rp[j] = v;
        }
        *(float4*)(&out[(((size_t)b * Cout + co) * Ho + ho) * Wo + w0 + tx * 4]) = r;
    }
}

extern "C" void kernel_launch(void* const* d_in, const int* in_sizes, int n_in,
                              void* d_out, int out_size, void* d_ws, size_t ws_size,
                              hipStream_t stream) {
    const float* in = (const float*)d_in[0];
    const float* off = (const float*)d_in[1];
    const float* msk = (const float*)d_in[2];
    const float* w = (const float*)d_in[3];
    const float* bias = (const float*)d_in[4];
    float* out = (float*)d_out;

    const size_t needX = (size_t)8 * 128 * 128 * 64 * 2;   // 16 MB NHWC bf16
    const size_t xoff = 131072;                            // wA region (73728 B used)
    if (ws_size >= xoff + needX) {
        unsigned short* wAb = (unsigned short*)d_ws;
        unsigned short* xnb = (unsigned short*)((char*)d_ws + xoff);
        prep_w<<<144, 256, 0, stream>>>(w, wAb);
        to_nhwc<<<2048, 256, 0, stream>>>(in, xnb);
        dcn_mfma<<<2048, 256, 0, stream>>>(xnb, off, msk, wAb, bias, out);
    } else {
        float* wT = (float*)d_ws;                          // 147456 B
        reorder_weight<<<(Cout * Cin * Kt + 255) / 256, 256, 0, stream>>>(w, wT);
        dcn_kernel<<<(B * Ho * Wo) / NT, 256, 0, stream>>>(in, off, msk, wT, bias, out);
    }
}